// Round 9
// baseline (1763.890 us; speedup 1.0000x reference)
//
#include <hip/hip_runtime.h>
#include <stdint.h>

typedef __attribute__((ext_vector_type(8)))  short   short8;
typedef __attribute__((ext_vector_type(8)))  unsigned short ushort8;
typedef __attribute__((ext_vector_type(8)))  __bf16  bf16x8;
typedef __attribute__((ext_vector_type(4)))  float   floatx4;
typedef __attribute__((ext_vector_type(4)))  unsigned short ushort4v;

#define AS1 __attribute__((address_space(1)))
#define AS3 __attribute__((address_space(3)))

__device__ __forceinline__ unsigned short f2bf(float f) {
  unsigned u = __builtin_bit_cast(unsigned, f);
  u = (u + 0x7FFFu + ((u >> 16) & 1u)) >> 16;   // RNE
  return (unsigned short)u;
}

// ---------------- f32 -> bf16 convert (n multiple of 1024) ----------------
__global__ __launch_bounds__(256) void convert_bf16(const float* __restrict__ src,
                                                    unsigned short* __restrict__ dst,
                                                    int n) {
  int i = (blockIdx.x * 256 + threadIdx.x) * 4;
  if (i >= n) return;
  float4 v = *(const float4*)(src + i);
  ushort4v o;
  o.x = f2bf(v.x); o.y = f2bf(v.y); o.z = f2bf(v.z); o.w = f2bf(v.w);
  *(ushort4v*)(dst + i) = o;
}

// ---------------- int64-vs-int32 id layout detection ----------------
__global__ __launch_bounds__(256) void detect_i64(const int* __restrict__ idbuf,
                                                  int* __restrict__ flag) {
  int v = 0;
  for (int i = threadIdx.x; i < 2048; i += 256) v |= idbuf[2 * i + 1];
  if (v != 0) atomicOr(flag, 1);
}

// ---------------- gather rows of emb -> bf16 x ----------------
__global__ __launch_bounds__(256) void gather_embed(const int* __restrict__ ids,
                                                    const float* __restrict__ emb,
                                                    unsigned short* __restrict__ xbf,
                                                    const int* __restrict__ flag) {
  int i = blockIdx.x;                      // 0..4095 (b*256+s)
  int row = (*flag != 0) ? ids[i] : ids[2 * i];   // int32 vs int64 layout
  const float* src = emb + (size_t)row * 1024 + threadIdx.x * 4;
  float4 v = *(const float4*)src;
  ushort4v o;
  o.x = f2bf(v.x); o.y = f2bf(v.y); o.z = f2bf(v.z); o.w = f2bf(v.w);
  *(ushort4v*)(xbf + (size_t)i * 1024 + threadIdx.x * 4) = o;
}

// ---------------- bf16 GEMM  C[rowmap(r),N] = A[r,K] * B[N,K]^T  (f32 out) ----
// rowmap: 0 identity; 1: r -> (r&255)*16 + (r>>8)   [b*256+s -> s*16+b]
//         2: r -> (r&15)*256 + (r>>4)               [t*16+b  -> b*256+t]
__global__ __launch_bounds__(256) void gemm_bt(const unsigned short* __restrict__ A,
                                               const unsigned short* __restrict__ B,
                                               float* __restrict__ C,
                                               int M, int N, int K, int rowmap) {
  __shared__ unsigned short lA[128 * 64];
  __shared__ unsigned short lB[128 * 64];
  const int nwg  = gridDim.x;
  const int wgid = blockIdx.x;
  const int q    = nwg >> 3;                       // XCD-aware swizzle (nwg % 8 == 0)
  const int swz  = (wgid & 7) * q + (wgid >> 3);
  const int ntx  = N >> 7;
  const int bx   = swz % ntx;
  const int by   = swz / ntx;
  const int tid  = threadIdx.x;
  const int lane = tid & 63;
  const int w    = tid >> 6;
  const int wr   = w >> 1, wc = w & 1;

  floatx4 acc[4][4];
#pragma unroll
  for (int m = 0; m < 4; ++m)
#pragma unroll
    for (int n = 0; n < 4; ++n) acc[m][n] = (floatx4){0.f, 0.f, 0.f, 0.f};

  const size_t rowA0 = (size_t)by * 128;
  const size_t colB0 = (size_t)bx * 128;

  for (int k0 = 0; k0 < K; k0 += 64) {
#pragma unroll
    for (int p = 0; p < 4; ++p) {
      int cc = p * 256 + tid;       // 16B chunk id, 0..1023
      int r  = cc >> 3;             // tile row 0..127
      int c8 = cc & 7;              // 16B chunk within row
      const unsigned short* srcA = A + (rowA0 + r) * K + k0 + c8 * 8;
      const unsigned short* srcB = B + (colB0 + r) * K + k0 + c8 * 8;
      __builtin_amdgcn_global_load_lds((const AS1 unsigned int*)srcA,
                                       (AS3 unsigned int*)&lA[cc * 8], 16, 0, 0);
      __builtin_amdgcn_global_load_lds((const AS1 unsigned int*)srcB,
                                       (AS3 unsigned int*)&lB[cc * 8], 16, 0, 0);
    }
    __syncthreads();
#pragma unroll
    for (int kk = 0; kk < 2; ++kk) {
      const int kofs = kk * 32 + (lane >> 4) * 8;
      bf16x8 af[4], bfv[4];
#pragma unroll
      for (int m = 0; m < 4; ++m) {
        int r = wr * 64 + m * 16 + (lane & 15);
        af[m] = *(const bf16x8*)&lA[r * 64 + kofs];
      }
#pragma unroll
      for (int n = 0; n < 4; ++n) {
        int r = wc * 64 + n * 16 + (lane & 15);
        bfv[n] = *(const bf16x8*)&lB[r * 64 + kofs];
      }
#pragma unroll
      for (int m = 0; m < 4; ++m)
#pragma unroll
        for (int n = 0; n < 4; ++n)
          acc[m][n] = __builtin_amdgcn_mfma_f32_16x16x32_bf16(af[m], bfv[n], acc[m][n], 0, 0, 0);
    }
    __syncthreads();
  }

#pragma unroll
  for (int m = 0; m < 4; ++m) {
#pragma unroll
    for (int j = 0; j < 4; ++j) {
      size_t row = rowA0 + wr * 64 + m * 16 + ((lane >> 4) * 4 + j);
      size_t orow = (rowmap == 0) ? row
                  : (rowmap == 1) ? ((row & 255) * 16 + (row >> 8))
                                  : ((row & 15) * 256 + (row >> 4));
      float* crow = C + orow * (size_t)N + colB0 + wc * 64 + (lane & 15);
#pragma unroll
      for (int n = 0; n < 4; ++n) crow[n * 16] = acc[m][n][j];
    }
  }
}

// ---------------- recurrence via MFMA: h_t = tanh(xin_t + h_{t-1} @ w_hh^T) ----
// ROUND-7 STRUCTURE (passed), ONE change: hst publish/poll at SYSTEM scope.
// Round-7 counters (FETCH=104GB = 195 retries/step at ~60cy period) proved the
// AGENT-scope poll loads were served by stale near caches — the consumer spins
// on a stale line until eviction (~µs), which set the 4.9µs step time. SYSTEM
// scope forces sc0+sc1 (bypass L1 + non-coherent per-XCD L2): detection now
// happens on the first ~900cy retry after the producer's write lands at the
// coherence point. NaN-sentinel correctness is scope-independent (staleness
// only ever delays, never corrupts).
__global__ __launch_bounds__(512) void rnn_mfma(const float* __restrict__ xin,         // [t*16+b][1024] f32
                                                const unsigned short* __restrict__ whh,// [1024][1024] bf16
                                                unsigned short* __restrict__ hst) {    // [256][16*1024] bf16, NaN-armed
  const int tid  = threadIdx.x;
  const int lane = tid & 63;
  const int w    = tid >> 6;        // 0..7: k-eighth
  const int n    = lane & 15;       // out col within tile / A batch row
  const int g    = lane >> 4;       // 0..3: k-subgroup within 32-wide MFMA step
  const int out_base = blockIdx.x * 16;

  __shared__ unsigned short wsh[16 * 1024];   // 32 KB swizzled weight slice
  __shared__ floatx4 red[2][8][64];           // 16 KB partials, double-buffered

  // ---- stage w_hh[out_base .. +16)[0..1024) -> LDS (swizzled 16B chunks) ----
#pragma unroll
  for (int p = 0; p < 4; ++p) {
    int cc = p * 512 + tid;              // 16B chunk id, 0..2047
    int r  = cc >> 7;                    // row 0..15
    int cb = (cc & 127) * 16;            // byte col 0..2047
    ushort8 v = *(const ushort8*)&whh[(size_t)(out_base + r) * 1024 + cb / 2];
    *(ushort8*)&wsh[((r * 2048 + cb) ^ ((r & 7) << 4)) / 2] = v;
  }
  __syncthreads();                       // weights ready

  const unsigned long long* hsrc64 = (const unsigned long long*)hst;

  for (int t = 0; t < 256; ++t) {
    // wave 0 prefetches xin for the tail: batch = g*4+jj, out = out_base+n
    float xi[4];
    if (w == 0) {
#pragma unroll
      for (int jj = 0; jj < 4; ++jj)
        xi[jj] = xin[(size_t)(t * 16 + g * 4 + jj) * 1024 + out_base + n];
    }

    floatx4 s4 = (floatx4){0.f, 0.f, 0.f, 0.f};
    if (t > 0) {
      // A-frags: h_{t-1}[batch=n][k = w*128 + ks*32 + g*8 .. +8], ks=0..3
      const unsigned long long* src =
          hsrc64 + ((size_t)(t - 1) * 4096 + (size_t)n * 256 + w * 32 + g * 2);
      unsigned long long lo[4], hi[4];
      for (;;) {
#pragma unroll
        for (int ks = 0; ks < 4; ++ks) {
          lo[ks] = __hip_atomic_load(src + ks * 8 + 0, __ATOMIC_RELAXED, __HIP_MEMORY_SCOPE_SYSTEM);
          hi[ks] = __hip_atomic_load(src + ks * 8 + 1, __ATOMIC_RELAXED, __HIP_MEMORY_SCOPE_SYSTEM);
        }
        unsigned bad = 0;
#pragma unroll
        for (int ks = 0; ks < 4; ++ks) {
          bad |= ((unsigned)lo[ks] == 0xFFFFFFFFu) | ((unsigned)(lo[ks] >> 32) == 0xFFFFFFFFu);
          bad |= ((unsigned)hi[ks] == 0xFFFFFFFFu) | ((unsigned)(hi[ks] >> 32) == 0xFFFFFFFFu);
        }
        if (!__any((int)bad)) break;     // every source dword is final
      }
      // compute once: wb from LDS (swizzled), 2 accumulation chains
      floatx4 a0 = (floatx4){0,0,0,0}, a1 = (floatx4){0,0,0,0};
#pragma unroll
      for (int ks = 0; ks < 4; ++ks) {
        int baddr = (n * 2048 + w * 256 + ks * 64 + g * 16) ^ ((n & 7) << 4);
        bf16x8 wb = *(const bf16x8*)&wsh[baddr / 2];
        bf16x8 af = __builtin_bit_cast(bf16x8, (ulonglong2){lo[ks], hi[ks]});
        if (ks & 1) a1 = __builtin_amdgcn_mfma_f32_16x16x32_bf16(af, wb, a1, 0, 0, 0);
        else        a0 = __builtin_amdgcn_mfma_f32_16x16x32_bf16(af, wb, a0, 0, 0, 0);
      }
      s4 = a0 + a1;
    }

    red[t & 1][w][lane] = s4;
    __syncthreads();                      // partials visible to wave 0

    if (w == 0) {
      floatx4 tot = red[t & 1][0][lane];
#pragma unroll
      for (int k = 1; k < 8; ++k) tot += red[t & 1][k][lane];
      float hv[4];
#pragma unroll
      for (int jj = 0; jj < 4; ++jj) {
        float s = tot[jj] + xi[jj];
        float e = __expf(2.0f * s);           // tanh = 1 - 2/(e^{2s}+1)
        hv[jj] = 1.0f - 2.0f * __builtin_amdgcn_rcpf(e + 1.0f);
      }
      // pair-pack with lane^1 so each store is a full dword (2 adjacent outs)
      float pv[4];
#pragma unroll
      for (int jj = 0; jj < 4; ++jj) pv[jj] = __shfl_xor(hv[jj], 1);
      const int ev = (lane & 1) == 0;
      const int jA = ev ? 0 : 2, jB = ev ? 1 : 3;
      unsigned dA = ev ? ((unsigned)f2bf(hv[jA]) | ((unsigned)f2bf(pv[jA]) << 16))
                       : ((unsigned)f2bf(pv[jA]) | ((unsigned)f2bf(hv[jA]) << 16));
      unsigned dB = ev ? ((unsigned)f2bf(hv[jB]) | ((unsigned)f2bf(pv[jB]) << 16))
                       : ((unsigned)f2bf(pv[jB]) | ((unsigned)f2bf(hv[jB]) << 16));
      unsigned* rowA = (unsigned*)&hst[(size_t)t * 16384 + (size_t)(g * 4 + jA) * 1024 + out_base + (n & ~1)];
      unsigned* rowB = (unsigned*)&hst[(size_t)t * 16384 + (size_t)(g * 4 + jB) * 1024 + out_base + (n & ~1)];
      __hip_atomic_store(rowA, dA, __ATOMIC_RELAXED, __HIP_MEMORY_SCOPE_SYSTEM);
      __hip_atomic_store(rowB, dB, __ATOMIC_RELAXED, __HIP_MEMORY_SCOPE_SYSTEM);
    }
  }
}

// ---------------- host launch ----------------
extern "C" void kernel_launch(void* const* d_in, const int* in_sizes, int n_in,
                              void* d_out, int out_size, void* d_ws, size_t ws_size,
                              hipStream_t stream) {
  const int*   ids  = (const int*)d_in[0];     // [16,256]
  const float* emb  = (const float*)d_in[1];   // [32000,1024]
  const float* w_hx = (const float*)d_in[2];   // [1024,1024]
  const float* w_hh = (const float*)d_in[3];   // [1024,1024]
  const float* w_yh = (const float*)d_in[4];   // [32000,1024]
  float*       out  = (float*)d_out;           // [16,256,32000]

  const int B = 16, S = 256, H = 1024, V = 32000;
  const int BS = B * S;

  char*  ws  = (char*)d_ws;
  size_t off = 0;
  auto alloc = [&](size_t bytes) {
    size_t cur = off;
    off += (bytes + 255) & ~(size_t)255;
    return (void*)(ws + cur);
  };

  unsigned short* whx_bf = (unsigned short*)alloc((size_t)H * H * 2);
  unsigned short* whh_bf = (unsigned short*)alloc((size_t)H * H * 2);
  unsigned short* wyh_bf = (unsigned short*)alloc((size_t)V * H * 2);
  unsigned short* x_bf   = (unsigned short*)alloc((size_t)BS * H * 2);
  float*          xin    = (float*)alloc((size_t)BS * H * 4);   // [t*16+b][H]
  unsigned short* hst    = (unsigned short*)alloc((size_t)BS * H * 2); // [t][b][H]
  int*            dflag  = (int*)alloc(256);

  // NaN-arm the step buffer every call (write-once data-as-flag; replay-safe).
  hipMemsetAsync(hst, 0xFF, (size_t)BS * H * 2, stream);
  hipMemsetAsync(dflag, 0, 256, stream);

  detect_i64<<<dim3(1), dim3(256), 0, stream>>>(ids, dflag);
  convert_bf16<<<dim3((H * H) / 1024), dim3(256), 0, stream>>>(w_hx, whx_bf, H * H);
  convert_bf16<<<dim3((H * H) / 1024), dim3(256), 0, stream>>>(w_hh, whh_bf, H * H);
  convert_bf16<<<dim3((V * H) / 1024), dim3(256), 0, stream>>>(w_yh, wyh_bf, V * H);
  gather_embed<<<dim3(BS), dim3(256), 0, stream>>>(ids, emb, x_bf, dflag);

  // xin[s*16+b] = x[b*256+s] @ w_hx^T : rowmap=1
  gemm_bt<<<dim3((BS / 128) * (H / 128)), dim3(256), 0, stream>>>(x_bf, whx_bf, xin, BS, H, H, 1);

  // sequential recurrence: 64 WGs x 8 waves, LDS weights, data-as-flag(NaN) sync
  rnn_mfma<<<dim3(64), dim3(512), 0, stream>>>(xin, whh_bf, hst);

  // logits[b*256+t] = h[t*16+b] @ w_yh^T : rowmap=2
  gemm_bt<<<dim3((BS / 128) * (V / 128)), dim3(256), 0, stream>>>(hst, wyh_bf, out, BS, V, H, 2);
}

// Round 10
// 1279.917 us; speedup vs baseline: 1.3781x; 1.3781x over previous
//
#include <hip/hip_runtime.h>
#include <stdint.h>

typedef __attribute__((ext_vector_type(8)))  short   short8;
typedef __attribute__((ext_vector_type(8)))  unsigned short ushort8;
typedef __attribute__((ext_vector_type(8)))  __bf16  bf16x8;
typedef __attribute__((ext_vector_type(4)))  float   floatx4;
typedef __attribute__((ext_vector_type(4)))  unsigned short ushort4v;
typedef __attribute__((ext_vector_type(4)))  unsigned int   uint4v;

#define AS1 __attribute__((address_space(1)))
#define AS3 __attribute__((address_space(3)))

__device__ __forceinline__ unsigned short f2bf(float f) {
  unsigned u = __builtin_bit_cast(unsigned, f);
  u = (u + 0x7FFFu + ((u >> 16) & 1u)) >> 16;   // RNE
  return (unsigned short)u;
}

// ---------------- f32 -> bf16 convert (n multiple of 1024) ----------------
__global__ __launch_bounds__(256) void convert_bf16(const float* __restrict__ src,
                                                    unsigned short* __restrict__ dst,
                                                    int n) {
  int i = (blockIdx.x * 256 + threadIdx.x) * 4;
  if (i >= n) return;
  float4 v = *(const float4*)(src + i);
  ushort4v o;
  o.x = f2bf(v.x); o.y = f2bf(v.y); o.z = f2bf(v.z); o.w = f2bf(v.w);
  *(ushort4v*)(dst + i) = o;
}

// ---------------- int64-vs-int32 id layout detection ----------------
__global__ __launch_bounds__(256) void detect_i64(const int* __restrict__ idbuf,
                                                  int* __restrict__ flag) {
  int v = 0;
  for (int i = threadIdx.x; i < 2048; i += 256) v |= idbuf[2 * i + 1];
  if (v != 0) atomicOr(flag, 1);
}

// ---------------- gather rows of emb -> bf16 x ----------------
__global__ __launch_bounds__(256) void gather_embed(const int* __restrict__ ids,
                                                    const float* __restrict__ emb,
                                                    unsigned short* __restrict__ xbf,
                                                    const int* __restrict__ flag) {
  int i = blockIdx.x;                      // 0..4095 (b*256+s)
  int row = (*flag != 0) ? ids[i] : ids[2 * i];   // int32 vs int64 layout
  const float* src = emb + (size_t)row * 1024 + threadIdx.x * 4;
  float4 v = *(const float4*)src;
  ushort4v o;
  o.x = f2bf(v.x); o.y = f2bf(v.y); o.z = f2bf(v.z); o.w = f2bf(v.w);
  *(ushort4v*)(xbf + (size_t)i * 1024 + threadIdx.x * 4) = o;
}

// ---------------- bf16 GEMM  C[rowmap(r),N] = A[r,K] * B[N,K]^T  (f32 out) ----
// rowmap: 0 identity; 1: r -> (r&255)*16 + (r>>8)   [b*256+s -> s*16+b]
//         2: r -> (r&15)*256 + (r>>4)               [t*16+b  -> b*256+t]
__global__ __launch_bounds__(256) void gemm_bt(const unsigned short* __restrict__ A,
                                               const unsigned short* __restrict__ B,
                                               float* __restrict__ C,
                                               int M, int N, int K, int rowmap) {
  __shared__ unsigned short lA[128 * 64];
  __shared__ unsigned short lB[128 * 64];
  const int nwg  = gridDim.x;
  const int wgid = blockIdx.x;
  const int q    = nwg >> 3;                       // XCD-aware swizzle (nwg % 8 == 0)
  const int swz  = (wgid & 7) * q + (wgid >> 3);
  const int ntx  = N >> 7;
  const int bx   = swz % ntx;
  const int by   = swz / ntx;
  const int tid  = threadIdx.x;
  const int lane = tid & 63;
  const int w    = tid >> 6;
  const int wr   = w >> 1, wc = w & 1;

  floatx4 acc[4][4];
#pragma unroll
  for (int m = 0; m < 4; ++m)
#pragma unroll
    for (int n = 0; n < 4; ++n) acc[m][n] = (floatx4){0.f, 0.f, 0.f, 0.f};

  const size_t rowA0 = (size_t)by * 128;
  const size_t colB0 = (size_t)bx * 128;

  for (int k0 = 0; k0 < K; k0 += 64) {
#pragma unroll
    for (int p = 0; p < 4; ++p) {
      int cc = p * 256 + tid;       // 16B chunk id, 0..1023
      int r  = cc >> 3;             // tile row 0..127
      int c8 = cc & 7;              // 16B chunk within row
      const unsigned short* srcA = A + (rowA0 + r) * K + k0 + c8 * 8;
      const unsigned short* srcB = B + (colB0 + r) * K + k0 + c8 * 8;
      __builtin_amdgcn_global_load_lds((const AS1 unsigned int*)srcA,
                                       (AS3 unsigned int*)&lA[cc * 8], 16, 0, 0);
      __builtin_amdgcn_global_load_lds((const AS1 unsigned int*)srcB,
                                       (AS3 unsigned int*)&lB[cc * 8], 16, 0, 0);
    }
    __syncthreads();
#pragma unroll
    for (int kk = 0; kk < 2; ++kk) {
      const int kofs = kk * 32 + (lane >> 4) * 8;
      bf16x8 af[4], bfv[4];
#pragma unroll
      for (int m = 0; m < 4; ++m) {
        int r = wr * 64 + m * 16 + (lane & 15);
        af[m] = *(const bf16x8*)&lA[r * 64 + kofs];
      }
#pragma unroll
      for (int n = 0; n < 4; ++n) {
        int r = wc * 64 + n * 16 + (lane & 15);
        bfv[n] = *(const bf16x8*)&lB[r * 64 + kofs];
      }
#pragma unroll
      for (int m = 0; m < 4; ++m)
#pragma unroll
        for (int n = 0; n < 4; ++n)
          acc[m][n] = __builtin_amdgcn_mfma_f32_16x16x32_bf16(af[m], bfv[n], acc[m][n], 0, 0, 0);
    }
    __syncthreads();
  }

#pragma unroll
  for (int m = 0; m < 4; ++m) {
#pragma unroll
    for (int j = 0; j < 4; ++j) {
      size_t row = rowA0 + wr * 64 + m * 16 + ((lane >> 4) * 4 + j);
      size_t orow = (rowmap == 0) ? row
                  : (rowmap == 1) ? ((row & 255) * 16 + (row >> 8))
                                  : ((row & 15) * 256 + (row >> 4));
      float* crow = C + orow * (size_t)N + colB0 + wc * 64 + (lane & 15);
#pragma unroll
      for (int n = 0; n < 4; ++n) crow[n * 16] = acc[m][n][j];
    }
  }
}

// ---------------- recurrence via MFMA: h_t = tanh(xin_t + h_{t-1} @ w_hh^T) ----
// ROUND-7 STRUCTURE (passed), ONE change: publish/poll via inline-asm
// global ops with sc0 sc1 (bypass L1 AND the non-coherent per-XCD L2; reads
// and writes served at the coherence point). Round-8 proved __hip_atomic
// RELAXED emits identical code at AGENT and SYSTEM scope (null A/B), so the
// stale-cache spin (104 GB FETCH = ~195 retries/step at ~60cy = L1-hit spin,
// progress gated on producer L2 eviction) was never addressed. The sentinel
// check is register-tied to the vmcnt(0) asm ("+v") so uses can't be hoisted
// above the wait (rule #18, vmcnt analog).
__global__ __launch_bounds__(512) void rnn_mfma(const float* __restrict__ xin,         // [t*16+b][1024] f32
                                                const unsigned short* __restrict__ whh,// [1024][1024] bf16
                                                unsigned short* __restrict__ hst) {    // [256][16*1024] bf16, NaN-armed
  const int tid  = threadIdx.x;
  const int lane = tid & 63;
  const int w    = tid >> 6;        // 0..7: k-eighth
  const int n    = lane & 15;       // out col within tile / A batch row
  const int g    = lane >> 4;       // 0..3: k-subgroup within 32-wide MFMA step
  const int out_base = blockIdx.x * 16;

  __shared__ unsigned short wsh[16 * 1024];   // 32 KB swizzled weight slice
  __shared__ floatx4 red[2][8][64];           // 16 KB partials, double-buffered

  // ---- stage w_hh[out_base .. +16)[0..1024) -> LDS (swizzled 16B chunks) ----
#pragma unroll
  for (int p = 0; p < 4; ++p) {
    int cc = p * 512 + tid;              // 16B chunk id, 0..2047
    int r  = cc >> 7;                    // row 0..15
    int cb = (cc & 127) * 16;            // byte col 0..2047
    ushort8 v = *(const ushort8*)&whh[(size_t)(out_base + r) * 1024 + cb / 2];
    *(ushort8*)&wsh[((r * 2048 + cb) ^ ((r & 7) << 4)) / 2] = v;
  }
  __syncthreads();                       // weights ready

  for (int t = 0; t < 256; ++t) {
    // wave 0 prefetches xin for the tail: batch = g*4+jj, out = out_base+n
    float xi[4];
    if (w == 0) {
#pragma unroll
      for (int jj = 0; jj < 4; ++jj)
        xi[jj] = xin[(size_t)(t * 16 + g * 4 + jj) * 1024 + out_base + n];
    }

    floatx4 s4 = (floatx4){0.f, 0.f, 0.f, 0.f};
    if (t > 0) {
      // A-frags: h_{t-1}[batch=n][k = w*128 + ks*32 + g*8 .. +8], ks=0..3
      // byte base of ks=0 chunk; ks stride = 64 B (32 bf16)
      const char* base = (const char*)hst +
          ((size_t)(t - 1) * 16384 + (size_t)n * 1024 + w * 128 + g * 8) * 2;
      uint4v q0, q1, q2, q3;
      for (;;) {
        // coherence-point loads: bypass L1 + per-XCD L2 (sc0 sc1)
        asm volatile("global_load_dwordx4 %0, %1, off sc0 sc1"            : "=v"(q0) : "v"(base) : "memory");
        asm volatile("global_load_dwordx4 %0, %1, off offset:64 sc0 sc1"  : "=v"(q1) : "v"(base) : "memory");
        asm volatile("global_load_dwordx4 %0, %1, off offset:128 sc0 sc1" : "=v"(q2) : "v"(base) : "memory");
        asm volatile("global_load_dwordx4 %0, %1, off offset:192 sc0 sc1" : "=v"(q3) : "v"(base) : "memory");
        // wait for all 4; "+v" ties q* to this asm so checks can't hoist above
        asm volatile("s_waitcnt vmcnt(0)"
                     : "+v"(q0), "+v"(q1), "+v"(q2), "+v"(q3) :: "memory");
        unsigned bad = 0;
#pragma unroll
        for (int e = 0; e < 4; ++e) {
          bad |= (q0[e] == 0xFFFFFFFFu);
          bad |= (q1[e] == 0xFFFFFFFFu);
          bad |= (q2[e] == 0xFFFFFFFFu);
          bad |= (q3[e] == 0xFFFFFFFFu);
        }
        if (!__any((int)bad)) break;     // every source dword is final
      }
      // compute once: wb from LDS (swizzled), 2 accumulation chains
      floatx4 a0 = (floatx4){0,0,0,0}, a1 = (floatx4){0,0,0,0};
      {
        bf16x8 wb0 = *(const bf16x8*)&wsh[((n * 2048 + w * 256 +   0 + g * 16) ^ ((n & 7) << 4)) / 2];
        bf16x8 wb1 = *(const bf16x8*)&wsh[((n * 2048 + w * 256 +  64 + g * 16) ^ ((n & 7) << 4)) / 2];
        bf16x8 wb2 = *(const bf16x8*)&wsh[((n * 2048 + w * 256 + 128 + g * 16) ^ ((n & 7) << 4)) / 2];
        bf16x8 wb3 = *(const bf16x8*)&wsh[((n * 2048 + w * 256 + 192 + g * 16) ^ ((n & 7) << 4)) / 2];
        a0 = __builtin_amdgcn_mfma_f32_16x16x32_bf16(__builtin_bit_cast(bf16x8, q0), wb0, a0, 0, 0, 0);
        a1 = __builtin_amdgcn_mfma_f32_16x16x32_bf16(__builtin_bit_cast(bf16x8, q1), wb1, a1, 0, 0, 0);
        a0 = __builtin_amdgcn_mfma_f32_16x16x32_bf16(__builtin_bit_cast(bf16x8, q2), wb2, a0, 0, 0, 0);
        a1 = __builtin_amdgcn_mfma_f32_16x16x32_bf16(__builtin_bit_cast(bf16x8, q3), wb3, a1, 0, 0, 0);
      }
      s4 = a0 + a1;
    }

    red[t & 1][w][lane] = s4;
    __syncthreads();                      // partials visible to wave 0

    if (w == 0) {
      floatx4 tot = red[t & 1][0][lane];
#pragma unroll
      for (int k = 1; k < 8; ++k) tot += red[t & 1][k][lane];
      float hv[4];
#pragma unroll
      for (int jj = 0; jj < 4; ++jj) {
        float s = tot[jj] + xi[jj];
        float e = __expf(2.0f * s);           // tanh = 1 - 2/(e^{2s}+1)
        hv[jj] = 1.0f - 2.0f * __builtin_amdgcn_rcpf(e + 1.0f);
      }
      // pair-pack with lane^1 so each store is a full dword (2 adjacent outs)
      float pv[4];
#pragma unroll
      for (int jj = 0; jj < 4; ++jj) pv[jj] = __shfl_xor(hv[jj], 1);
      const int ev = (lane & 1) == 0;
      const int jA = ev ? 0 : 2, jB = ev ? 1 : 3;
      unsigned dA = ev ? ((unsigned)f2bf(hv[jA]) | ((unsigned)f2bf(pv[jA]) << 16))
                       : ((unsigned)f2bf(pv[jA]) | ((unsigned)f2bf(hv[jA]) << 16));
      unsigned dB = ev ? ((unsigned)f2bf(hv[jB]) | ((unsigned)f2bf(pv[jB]) << 16))
                       : ((unsigned)f2bf(pv[jB]) | ((unsigned)f2bf(hv[jB]) << 16));
      char* rowA = (char*)hst + ((size_t)t * 16384 + (size_t)(g * 4 + jA) * 1024 + out_base + (n & ~1)) * 2;
      char* rowB = (char*)hst + ((size_t)t * 16384 + (size_t)(g * 4 + jB) * 1024 + out_base + (n & ~1)) * 2;
      // write-through to the coherence point (sc0 sc1)
      asm volatile("global_store_dword %0, %1, off sc0 sc1" :: "v"(rowA), "v"(dA) : "memory");
      asm volatile("global_store_dword %0, %1, off sc0 sc1" :: "v"(rowB), "v"(dB) : "memory");
    }
  }
}

// ---------------- host launch ----------------
extern "C" void kernel_launch(void* const* d_in, const int* in_sizes, int n_in,
                              void* d_out, int out_size, void* d_ws, size_t ws_size,
                              hipStream_t stream) {
  const int*   ids  = (const int*)d_in[0];     // [16,256]
  const float* emb  = (const float*)d_in[1];   // [32000,1024]
  const float* w_hx = (const float*)d_in[2];   // [1024,1024]
  const float* w_hh = (const float*)d_in[3];   // [1024,1024]
  const float* w_yh = (const float*)d_in[4];   // [32000,1024]
  float*       out  = (float*)d_out;           // [16,256,32000]

  const int B = 16, S = 256, H = 1024, V = 32000;
  const int BS = B * S;

  char*  ws  = (char*)d_ws;
  size_t off = 0;
  auto alloc = [&](size_t bytes) {
    size_t cur = off;
    off += (bytes + 255) & ~(size_t)255;
    return (void*)(ws + cur);
  };

  unsigned short* whx_bf = (unsigned short*)alloc((size_t)H * H * 2);
  unsigned short* whh_bf = (unsigned short*)alloc((size_t)H * H * 2);
  unsigned short* wyh_bf = (unsigned short*)alloc((size_t)V * H * 2);
  unsigned short* x_bf   = (unsigned short*)alloc((size_t)BS * H * 2);
  float*          xin    = (float*)alloc((size_t)BS * H * 4);   // [t*16+b][H]
  unsigned short* hst    = (unsigned short*)alloc((size_t)BS * H * 2); // [t][b][H]
  int*            dflag  = (int*)alloc(256);

  // NaN-arm the step buffer every call (write-once data-as-flag; replay-safe).
  hipMemsetAsync(hst, 0xFF, (size_t)BS * H * 2, stream);
  hipMemsetAsync(dflag, 0, 256, stream);

  detect_i64<<<dim3(1), dim3(256), 0, stream>>>(ids, dflag);
  convert_bf16<<<dim3((H * H) / 1024), dim3(256), 0, stream>>>(w_hx, whx_bf, H * H);
  convert_bf16<<<dim3((H * H) / 1024), dim3(256), 0, stream>>>(w_hh, whh_bf, H * H);
  convert_bf16<<<dim3((V * H) / 1024), dim3(256), 0, stream>>>(w_yh, wyh_bf, V * H);
  gather_embed<<<dim3(BS), dim3(256), 0, stream>>>(ids, emb, x_bf, dflag);

  // xin[s*16+b] = x[b*256+s] @ w_hx^T : rowmap=1
  gemm_bt<<<dim3((BS / 128) * (H / 128)), dim3(256), 0, stream>>>(x_bf, whx_bf, xin, BS, H, H, 1);

  // sequential recurrence: 64 WGs x 8 waves, LDS weights, data-as-flag(NaN) sync
  rnn_mfma<<<dim3(64), dim3(512), 0, stream>>>(xin, whh_bf, hst);

  // logits[b*256+t] = h[t*16+b] @ w_yh^T : rowmap=2
  gemm_bt<<<dim3((BS / 128) * (V / 128)), dim3(256), 0, stream>>>(hst, wyh_bf, out, BS, V, H, 2);
}

// Round 11
// 1261.887 us; speedup vs baseline: 1.3978x; 1.0143x over previous
//
#include <hip/hip_runtime.h>
#include <stdint.h>

typedef __attribute__((ext_vector_type(8)))  short   short8;
typedef __attribute__((ext_vector_type(8)))  unsigned short ushort8;
typedef __attribute__((ext_vector_type(8)))  __bf16  bf16x8;
typedef __attribute__((ext_vector_type(4)))  float   floatx4;
typedef __attribute__((ext_vector_type(4)))  unsigned short ushort4v;
typedef __attribute__((ext_vector_type(4)))  unsigned int   uint4v;

#define AS1 __attribute__((address_space(1)))
#define AS3 __attribute__((address_space(3)))

__device__ __forceinline__ unsigned short f2bf(float f) {
  unsigned u = __builtin_bit_cast(unsigned, f);
  u = (u + 0x7FFFu + ((u >> 16) & 1u)) >> 16;   // RNE
  return (unsigned short)u;
}

// ---------------- f32 -> bf16 convert (n multiple of 1024) ----------------
__global__ __launch_bounds__(256) void convert_bf16(const float* __restrict__ src,
                                                    unsigned short* __restrict__ dst,
                                                    int n) {
  int i = (blockIdx.x * 256 + threadIdx.x) * 4;
  if (i >= n) return;
  float4 v = *(const float4*)(src + i);
  ushort4v o;
  o.x = f2bf(v.x); o.y = f2bf(v.y); o.z = f2bf(v.z); o.w = f2bf(v.w);
  *(ushort4v*)(dst + i) = o;
}

// ---------------- int64-vs-int32 id layout detection ----------------
__global__ __launch_bounds__(256) void detect_i64(const int* __restrict__ idbuf,
                                                  int* __restrict__ flag) {
  int v = 0;
  for (int i = threadIdx.x; i < 2048; i += 256) v |= idbuf[2 * i + 1];
  if (v != 0) atomicOr(flag, 1);
}

// ---------------- gather rows of emb -> bf16 x ----------------
__global__ __launch_bounds__(256) void gather_embed(const int* __restrict__ ids,
                                                    const float* __restrict__ emb,
                                                    unsigned short* __restrict__ xbf,
                                                    const int* __restrict__ flag) {
  int i = blockIdx.x;                      // 0..4095 (b*256+s)
  int row = (*flag != 0) ? ids[i] : ids[2 * i];   // int32 vs int64 layout
  const float* src = emb + (size_t)row * 1024 + threadIdx.x * 4;
  float4 v = *(const float4*)src;
  ushort4v o;
  o.x = f2bf(v.x); o.y = f2bf(v.y); o.z = f2bf(v.z); o.w = f2bf(v.w);
  *(ushort4v*)(xbf + (size_t)i * 1024 + threadIdx.x * 4) = o;
}

// ---------------- bf16 GEMM  C[rowmap(r),N] = A[r,K] * B[N,K]^T  (f32 out) ----
// rowmap: 0 identity; 1: r -> (r&255)*16 + (r>>8)   [b*256+s -> s*16+b]
//         2: r -> (r&15)*256 + (r>>4)               [t*16+b  -> b*256+t]
__global__ __launch_bounds__(256) void gemm_bt(const unsigned short* __restrict__ A,
                                               const unsigned short* __restrict__ B,
                                               float* __restrict__ C,
                                               int M, int N, int K, int rowmap) {
  __shared__ unsigned short lA[128 * 64];
  __shared__ unsigned short lB[128 * 64];
  const int nwg  = gridDim.x;
  const int wgid = blockIdx.x;
  const int q    = nwg >> 3;                       // XCD-aware swizzle (nwg % 8 == 0)
  const int swz  = (wgid & 7) * q + (wgid >> 3);
  const int ntx  = N >> 7;
  const int bx   = swz % ntx;
  const int by   = swz / ntx;
  const int tid  = threadIdx.x;
  const int lane = tid & 63;
  const int w    = tid >> 6;
  const int wr   = w >> 1, wc = w & 1;

  floatx4 acc[4][4];
#pragma unroll
  for (int m = 0; m < 4; ++m)
#pragma unroll
    for (int n = 0; n < 4; ++n) acc[m][n] = (floatx4){0.f, 0.f, 0.f, 0.f};

  const size_t rowA0 = (size_t)by * 128;
  const size_t colB0 = (size_t)bx * 128;

  for (int k0 = 0; k0 < K; k0 += 64) {
#pragma unroll
    for (int p = 0; p < 4; ++p) {
      int cc = p * 256 + tid;       // 16B chunk id, 0..1023
      int r  = cc >> 3;             // tile row 0..127
      int c8 = cc & 7;              // 16B chunk within row
      const unsigned short* srcA = A + (rowA0 + r) * K + k0 + c8 * 8;
      const unsigned short* srcB = B + (colB0 + r) * K + k0 + c8 * 8;
      __builtin_amdgcn_global_load_lds((const AS1 unsigned int*)srcA,
                                       (AS3 unsigned int*)&lA[cc * 8], 16, 0, 0);
      __builtin_amdgcn_global_load_lds((const AS1 unsigned int*)srcB,
                                       (AS3 unsigned int*)&lB[cc * 8], 16, 0, 0);
    }
    __syncthreads();
#pragma unroll
    for (int kk = 0; kk < 2; ++kk) {
      const int kofs = kk * 32 + (lane >> 4) * 8;
      bf16x8 af[4], bfv[4];
#pragma unroll
      for (int m = 0; m < 4; ++m) {
        int r = wr * 64 + m * 16 + (lane & 15);
        af[m] = *(const bf16x8*)&lA[r * 64 + kofs];
      }
#pragma unroll
      for (int n = 0; n < 4; ++n) {
        int r = wc * 64 + n * 16 + (lane & 15);
        bfv[n] = *(const bf16x8*)&lB[r * 64 + kofs];
      }
#pragma unroll
      for (int m = 0; m < 4; ++m)
#pragma unroll
        for (int n = 0; n < 4; ++n)
          acc[m][n] = __builtin_amdgcn_mfma_f32_16x16x32_bf16(af[m], bfv[n], acc[m][n], 0, 0, 0);
    }
    __syncthreads();
  }

#pragma unroll
  for (int m = 0; m < 4; ++m) {
#pragma unroll
    for (int j = 0; j < 4; ++j) {
      size_t row = rowA0 + wr * 64 + m * 16 + ((lane >> 4) * 4 + j);
      size_t orow = (rowmap == 0) ? row
                  : (rowmap == 1) ? ((row & 255) * 16 + (row >> 8))
                                  : ((row & 15) * 256 + (row >> 4));
      float* crow = C + orow * (size_t)N + colB0 + wc * 64 + (lane & 15);
#pragma unroll
      for (int n = 0; n < 4; ++n) crow[n * 16] = acc[m][n][j];
    }
  }
}

// ---------------- recurrence via MFMA: h_t = tanh(xin_t + h_{t-1} @ w_hh^T) ----
// ROUND-9 STRUCTURE (passed, 773µs), ONE change: flag-based release/acquire.
// Round-9 counters (FETCH still 90GB, ~170 retries/step x 4KB) showed the
// data-poll itself pushes ~10TB/s at the coherence point — congesting every
// hop on the serial chain (3.0µs/step vs ~0.9µs hop model). Now:
//   producer: data stores sc0 sc1 -> vmcnt(0) (acked at IF) -> flags[wg]=t+1
//   consumer: poll 8 flag dwords (512B/retry, 8x less traffic); then ONE data
//             load. NaN-sentinel retry loop kept as correctness backstop
//             (steady state: single pass).
__global__ __launch_bounds__(512) void rnn_mfma(const float* __restrict__ xin,         // [t*16+b][1024] f32
                                                const unsigned short* __restrict__ whh,// [1024][1024] bf16
                                                unsigned short* __restrict__ hst,      // [256][16*1024] bf16, NaN-armed
                                                unsigned* __restrict__ flags) {        // [64] x 64B-strided, 0-armed
  const int tid  = threadIdx.x;
  const int lane = tid & 63;
  const int w    = tid >> 6;        // 0..7: k-eighth
  const int n    = lane & 15;       // out col within tile / A batch row
  const int g    = lane >> 4;       // 0..3: k-subgroup within 32-wide MFMA step
  const int out_base = blockIdx.x * 16;

  __shared__ unsigned short wsh[16 * 1024];   // 32 KB swizzled weight slice
  __shared__ floatx4 red[2][8][64];           // 16 KB partials, double-buffered

  // ---- stage w_hh[out_base .. +16)[0..1024) -> LDS (swizzled 16B chunks) ----
#pragma unroll
  for (int p = 0; p < 4; ++p) {
    int cc = p * 512 + tid;              // 16B chunk id, 0..2047
    int r  = cc >> 7;                    // row 0..15
    int cb = (cc & 127) * 16;            // byte col 0..2047
    ushort8 v = *(const ushort8*)&whh[(size_t)(out_base + r) * 1024 + cb / 2];
    *(ushort8*)&wsh[((r * 2048 + cb) ^ ((r & 7) << 4)) / 2] = v;
  }
  __syncthreads();                       // weights ready

  // consumer flag address: wave w's k-eighth is produced by WGs w*8 .. w*8+7
  const char* my_flag_addr = (const char*)flags + (size_t)(w * 8 + (lane & 7)) * 64;
  // producer flag address (this WG's own flag)
  char* pub_flag_addr = (char*)flags + (size_t)blockIdx.x * 64;

  for (int t = 0; t < 256; ++t) {
    // wave 0 prefetches xin for the tail: batch = g*4+jj, out = out_base+n
    float xi[4];
    if (w == 0) {
#pragma unroll
      for (int jj = 0; jj < 4; ++jj)
        xi[jj] = xin[(size_t)(t * 16 + g * 4 + jj) * 1024 + out_base + n];
    }

    floatx4 s4 = (floatx4){0.f, 0.f, 0.f, 0.f};
    if (t > 0) {
      // ---- acquire: poll the 8 producer flags (512B/retry, IF-coherent) ----
      for (;;) {
        unsigned fv;
        asm volatile("global_load_dword %0, %1, off sc0 sc1" : "=v"(fv) : "v"(my_flag_addr) : "memory");
        asm volatile("s_waitcnt vmcnt(0)" : "+v"(fv) :: "memory");
        if (__all((int)(fv >= (unsigned)t))) break;
      }
      // ---- data load (once in steady state; sentinel loop as backstop) ----
      const char* base = (const char*)hst +
          ((size_t)(t - 1) * 16384 + (size_t)n * 1024 + w * 128 + g * 8) * 2;
      uint4v q0, q1, q2, q3;
      for (;;) {
        asm volatile("global_load_dwordx4 %0, %1, off sc0 sc1"            : "=v"(q0) : "v"(base) : "memory");
        asm volatile("global_load_dwordx4 %0, %1, off offset:64 sc0 sc1"  : "=v"(q1) : "v"(base) : "memory");
        asm volatile("global_load_dwordx4 %0, %1, off offset:128 sc0 sc1" : "=v"(q2) : "v"(base) : "memory");
        asm volatile("global_load_dwordx4 %0, %1, off offset:192 sc0 sc1" : "=v"(q3) : "v"(base) : "memory");
        asm volatile("s_waitcnt vmcnt(0)"
                     : "+v"(q0), "+v"(q1), "+v"(q2), "+v"(q3) :: "memory");
        unsigned bad = 0;
#pragma unroll
        for (int e = 0; e < 4; ++e) {
          bad |= (q0[e] == 0xFFFFFFFFu);
          bad |= (q1[e] == 0xFFFFFFFFu);
          bad |= (q2[e] == 0xFFFFFFFFu);
          bad |= (q3[e] == 0xFFFFFFFFu);
        }
        if (!__any((int)bad)) break;     // every source dword is final
      }
      // compute once: wb from LDS (swizzled), 2 accumulation chains
      floatx4 a0 = (floatx4){0,0,0,0}, a1 = (floatx4){0,0,0,0};
      {
        bf16x8 wb0 = *(const bf16x8*)&wsh[((n * 2048 + w * 256 +   0 + g * 16) ^ ((n & 7) << 4)) / 2];
        bf16x8 wb1 = *(const bf16x8*)&wsh[((n * 2048 + w * 256 +  64 + g * 16) ^ ((n & 7) << 4)) / 2];
        bf16x8 wb2 = *(const bf16x8*)&wsh[((n * 2048 + w * 256 + 128 + g * 16) ^ ((n & 7) << 4)) / 2];
        bf16x8 wb3 = *(const bf16x8*)&wsh[((n * 2048 + w * 256 + 192 + g * 16) ^ ((n & 7) << 4)) / 2];
        a0 = __builtin_amdgcn_mfma_f32_16x16x32_bf16(__builtin_bit_cast(bf16x8, q0), wb0, a0, 0, 0, 0);
        a1 = __builtin_amdgcn_mfma_f32_16x16x32_bf16(__builtin_bit_cast(bf16x8, q1), wb1, a1, 0, 0, 0);
        a0 = __builtin_amdgcn_mfma_f32_16x16x32_bf16(__builtin_bit_cast(bf16x8, q2), wb2, a0, 0, 0, 0);
        a1 = __builtin_amdgcn_mfma_f32_16x16x32_bf16(__builtin_bit_cast(bf16x8, q3), wb3, a1, 0, 0, 0);
      }
      s4 = a0 + a1;
    }

    red[t & 1][w][lane] = s4;
    __syncthreads();                      // partials visible to wave 0

    if (w == 0) {
      floatx4 tot = red[t & 1][0][lane];
#pragma unroll
      for (int k = 1; k < 8; ++k) tot += red[t & 1][k][lane];
      float hv[4];
#pragma unroll
      for (int jj = 0; jj < 4; ++jj) {
        float s = tot[jj] + xi[jj];
        float e = __expf(2.0f * s);           // tanh = 1 - 2/(e^{2s}+1)
        hv[jj] = 1.0f - 2.0f * __builtin_amdgcn_rcpf(e + 1.0f);
      }
      // pair-pack with lane^1 so each store is a full dword (2 adjacent outs)
      float pv[4];
#pragma unroll
      for (int jj = 0; jj < 4; ++jj) pv[jj] = __shfl_xor(hv[jj], 1);
      const int ev = (lane & 1) == 0;
      const int jA = ev ? 0 : 2, jB = ev ? 1 : 3;
      unsigned dA = ev ? ((unsigned)f2bf(hv[jA]) | ((unsigned)f2bf(pv[jA]) << 16))
                       : ((unsigned)f2bf(pv[jA]) | ((unsigned)f2bf(hv[jA]) << 16));
      unsigned dB = ev ? ((unsigned)f2bf(hv[jB]) | ((unsigned)f2bf(pv[jB]) << 16))
                       : ((unsigned)f2bf(pv[jB]) | ((unsigned)f2bf(hv[jB]) << 16));
      char* rowA = (char*)hst + ((size_t)t * 16384 + (size_t)(g * 4 + jA) * 1024 + out_base + (n & ~1)) * 2;
      char* rowB = (char*)hst + ((size_t)t * 16384 + (size_t)(g * 4 + jB) * 1024 + out_base + (n & ~1)) * 2;
      // release: data write-through -> ack -> flag store
      asm volatile("global_store_dword %0, %1, off sc0 sc1" :: "v"(rowA), "v"(dA) : "memory");
      asm volatile("global_store_dword %0, %1, off sc0 sc1" :: "v"(rowB), "v"(dB) : "memory");
      asm volatile("s_waitcnt vmcnt(0)" ::: "memory");
      if (lane == 0) {
        unsigned fval = (unsigned)(t + 1);
        asm volatile("global_store_dword %0, %1, off sc0 sc1" :: "v"(pub_flag_addr), "v"(fval) : "memory");
      }
    }
  }
}

// ---------------- host launch ----------------
extern "C" void kernel_launch(void* const* d_in, const int* in_sizes, int n_in,
                              void* d_out, int out_size, void* d_ws, size_t ws_size,
                              hipStream_t stream) {
  const int*   ids  = (const int*)d_in[0];     // [16,256]
  const float* emb  = (const float*)d_in[1];   // [32000,1024]
  const float* w_hx = (const float*)d_in[2];   // [1024,1024]
  const float* w_hh = (const float*)d_in[3];   // [1024,1024]
  const float* w_yh = (const float*)d_in[4];   // [32000,1024]
  float*       out  = (float*)d_out;           // [16,256,32000]

  const int B = 16, S = 256, H = 1024, V = 32000;
  const int BS = B * S;

  char*  ws  = (char*)d_ws;
  size_t off = 0;
  auto alloc = [&](size_t bytes) {
    size_t cur = off;
    off += (bytes + 255) & ~(size_t)255;
    return (void*)(ws + cur);
  };

  unsigned short* whx_bf = (unsigned short*)alloc((size_t)H * H * 2);
  unsigned short* whh_bf = (unsigned short*)alloc((size_t)H * H * 2);
  unsigned short* wyh_bf = (unsigned short*)alloc((size_t)V * H * 2);
  unsigned short* x_bf   = (unsigned short*)alloc((size_t)BS * H * 2);
  float*          xin    = (float*)alloc((size_t)BS * H * 4);   // [t*16+b][H]
  unsigned short* hst    = (unsigned short*)alloc((size_t)BS * H * 2); // [t][b][H]
  unsigned*       flags  = (unsigned*)alloc(64 * 64);           // 64 flags, 64B stride
  int*            dflag  = (int*)alloc(256);

  // Arm sentinels + flags every call (write-once data-as-flag; replay-safe).
  hipMemsetAsync(hst, 0xFF, (size_t)BS * H * 2, stream);
  hipMemsetAsync(flags, 0, 64 * 64, stream);
  hipMemsetAsync(dflag, 0, 256, stream);

  detect_i64<<<dim3(1), dim3(256), 0, stream>>>(ids, dflag);
  convert_bf16<<<dim3((H * H) / 1024), dim3(256), 0, stream>>>(w_hx, whx_bf, H * H);
  convert_bf16<<<dim3((H * H) / 1024), dim3(256), 0, stream>>>(w_hh, whh_bf, H * H);
  convert_bf16<<<dim3((V * H) / 1024), dim3(256), 0, stream>>>(w_yh, wyh_bf, V * H);
  gather_embed<<<dim3(BS), dim3(256), 0, stream>>>(ids, emb, x_bf, dflag);

  // xin[s*16+b] = x[b*256+s] @ w_hx^T : rowmap=1
  gemm_bt<<<dim3((BS / 128) * (H / 128)), dim3(256), 0, stream>>>(x_bf, whx_bf, xin, BS, H, H, 1);

  // sequential recurrence: 64 WGs x 8 waves, LDS weights, flag release/acquire
  rnn_mfma<<<dim3(64), dim3(512), 0, stream>>>(xin, whh_bf, hst, flags);

  // logits[b*256+t] = h[t*16+b] @ w_yh^T : rowmap=2
  gemm_bt<<<dim3((BS / 128) * (V / 128)), dim3(256), 0, stream>>>(hst, wyh_bf, out, BS, V, H, 2);
}

// Round 12
// 1030.782 us; speedup vs baseline: 1.7112x; 1.2242x over previous
//
#include <hip/hip_runtime.h>
#include <stdint.h>

typedef __attribute__((ext_vector_type(8)))  short   short8;
typedef __attribute__((ext_vector_type(8)))  unsigned short ushort8;
typedef __attribute__((ext_vector_type(8)))  __bf16  bf16x8;
typedef __attribute__((ext_vector_type(4)))  float   floatx4;
typedef __attribute__((ext_vector_type(4)))  unsigned short ushort4v;
typedef __attribute__((ext_vector_type(4)))  unsigned int   uint4v;

#define AS1 __attribute__((address_space(1)))
#define AS3 __attribute__((address_space(3)))

__device__ __forceinline__ unsigned short f2bf(float f) {
  unsigned u = __builtin_bit_cast(unsigned, f);
  u = (u + 0x7FFFu + ((u >> 16) & 1u)) >> 16;   // RNE
  return (unsigned short)u;
}

// ---------------- f32 -> bf16 convert (n multiple of 1024) ----------------
__global__ __launch_bounds__(256) void convert_bf16(const float* __restrict__ src,
                                                    unsigned short* __restrict__ dst,
                                                    int n) {
  int i = (blockIdx.x * 256 + threadIdx.x) * 4;
  if (i >= n) return;
  float4 v = *(const float4*)(src + i);
  ushort4v o;
  o.x = f2bf(v.x); o.y = f2bf(v.y); o.z = f2bf(v.z); o.w = f2bf(v.w);
  *(ushort4v*)(dst + i) = o;
}

// ---------------- int64-vs-int32 id layout detection ----------------
__global__ __launch_bounds__(256) void detect_i64(const int* __restrict__ idbuf,
                                                  int* __restrict__ flag) {
  int v = 0;
  for (int i = threadIdx.x; i < 2048; i += 256) v |= idbuf[2 * i + 1];
  if (v != 0) atomicOr(flag, 1);
}

// ---------------- gather rows of emb -> bf16 x ----------------
__global__ __launch_bounds__(256) void gather_embed(const int* __restrict__ ids,
                                                    const float* __restrict__ emb,
                                                    unsigned short* __restrict__ xbf,
                                                    const int* __restrict__ flag) {
  int i = blockIdx.x;                      // 0..4095 (b*256+s)
  int row = (*flag != 0) ? ids[i] : ids[2 * i];   // int32 vs int64 layout
  const float* src = emb + (size_t)row * 1024 + threadIdx.x * 4;
  float4 v = *(const float4*)src;
  ushort4v o;
  o.x = f2bf(v.x); o.y = f2bf(v.y); o.z = f2bf(v.z); o.w = f2bf(v.w);
  *(ushort4v*)(xbf + (size_t)i * 1024 + threadIdx.x * 4) = o;
}

// ---------------- bf16 GEMM  C[rowmap(r),N] = A[r,K] * B[N,K]^T  (f32 out) ----
// used for gemm1 (xin). rowmap 1: r -> (r&255)*16 + (r>>8)
__global__ __launch_bounds__(256) void gemm_bt(const unsigned short* __restrict__ A,
                                               const unsigned short* __restrict__ B,
                                               float* __restrict__ C,
                                               int M, int N, int K, int rowmap) {
  __shared__ unsigned short lA[128 * 64];
  __shared__ unsigned short lB[128 * 64];
  const int nwg  = gridDim.x;
  const int wgid = blockIdx.x;
  const int q    = nwg >> 3;                       // XCD-aware swizzle (nwg % 8 == 0)
  const int swz  = (wgid & 7) * q + (wgid >> 3);
  const int ntx  = N >> 7;
  const int bx   = swz % ntx;
  const int by   = swz / ntx;
  const int tid  = threadIdx.x;
  const int lane = tid & 63;
  const int w    = tid >> 6;
  const int wr   = w >> 1, wc = w & 1;

  floatx4 acc[4][4];
#pragma unroll
  for (int m = 0; m < 4; ++m)
#pragma unroll
    for (int n = 0; n < 4; ++n) acc[m][n] = (floatx4){0.f, 0.f, 0.f, 0.f};

  const size_t rowA0 = (size_t)by * 128;
  const size_t colB0 = (size_t)bx * 128;

  for (int k0 = 0; k0 < K; k0 += 64) {
#pragma unroll
    for (int p = 0; p < 4; ++p) {
      int cc = p * 256 + tid;       // 16B chunk id, 0..1023
      int r  = cc >> 3;             // tile row 0..127
      int c8 = cc & 7;              // 16B chunk within row
      const unsigned short* srcA = A + (rowA0 + r) * K + k0 + c8 * 8;
      const unsigned short* srcB = B + (colB0 + r) * K + k0 + c8 * 8;
      __builtin_amdgcn_global_load_lds((const AS1 unsigned int*)srcA,
                                       (AS3 unsigned int*)&lA[cc * 8], 16, 0, 0);
      __builtin_amdgcn_global_load_lds((const AS1 unsigned int*)srcB,
                                       (AS3 unsigned int*)&lB[cc * 8], 16, 0, 0);
    }
    __syncthreads();
#pragma unroll
    for (int kk = 0; kk < 2; ++kk) {
      const int kofs = kk * 32 + (lane >> 4) * 8;
      bf16x8 af[4], bfv[4];
#pragma unroll
      for (int m = 0; m < 4; ++m) {
        int r = wr * 64 + m * 16 + (lane & 15);
        af[m] = *(const bf16x8*)&lA[r * 64 + kofs];
      }
#pragma unroll
      for (int n = 0; n < 4; ++n) {
        int r = wc * 64 + n * 16 + (lane & 15);
        bfv[n] = *(const bf16x8*)&lB[r * 64 + kofs];
      }
#pragma unroll
      for (int m = 0; m < 4; ++m)
#pragma unroll
        for (int n = 0; n < 4; ++n)
          acc[m][n] = __builtin_amdgcn_mfma_f32_16x16x32_bf16(af[m], bfv[n], acc[m][n], 0, 0, 0);
    }
    __syncthreads();
  }

#pragma unroll
  for (int m = 0; m < 4; ++m) {
#pragma unroll
    for (int j = 0; j < 4; ++j) {
      size_t row = rowA0 + wr * 64 + m * 16 + ((lane >> 4) * 4 + j);
      size_t orow = (rowmap == 0) ? row
                  : (rowmap == 1) ? ((row & 255) * 16 + (row >> 8))
                                  : ((row & 15) * 256 + (row >> 4));
      float* crow = C + orow * (size_t)N + colB0 + wc * 64 + (lane & 15);
#pragma unroll
      for (int n = 0; n < 4; ++n) crow[n * 16] = acc[m][n][j];
    }
  }
}

// ---------------- FUSED: recurrence (WGs 0..63) + logits GEMM (WGs 64+) ------
// rnn: r10's proven protocol reshaped to 4 waves (wave = k-quarter, LDS
// weights, sc0sc1 publish, flag release, NaN backstop).
// gemm: grid-stride over 32x250 tiles rb-major; gate = all 64 flags >=
// 8*rb+8 (wave-0 poll, s_sleep-throttled); then the m97 128^2 k-loop.
// hst freshness for normal loads: every hst line is first touched after its
// flag gate; producer stores went sc0sc1 to the coherence point; consumer L2
// was invalidated at kernel launch -> miss -> fresh fetch.
__global__ __launch_bounds__(256, 3) void fused_rnn_logits(
    const float* __restrict__ xin,          // [t*16+b][1024] f32
    const unsigned short* __restrict__ whh, // [1024][1024] bf16
    unsigned short* __restrict__ hst,       // [256][16*1024] bf16, NaN-armed
    unsigned* __restrict__ flags,           // [64] x 64B-strided, 0-armed
    const unsigned short* __restrict__ wyh, // [32000][1024] bf16
    float* __restrict__ out,                // [16][256][32000] f32
    int G) {
  __shared__ __align__(16) char smem[40 * 1024];
  const int tid  = threadIdx.x;
  const int lane = tid & 63;
  const int w    = tid >> 6;        // 0..3

  if (blockIdx.x < 64) {
    // ======================= RNN path =======================
    unsigned short* wsh = (unsigned short*)smem;                       // 32 KB
    floatx4 (*red)[4][64] = (floatx4 (*)[4][64])(smem + 32768);        // 8 KB
    const int n = lane & 15;        // out col / batch row
    const int g = lane >> 4;        // 0..3 k-subgroup
    const int out_base = blockIdx.x * 16;

    // stage w_hh[out_base..+16)[0..1024) -> LDS, XOR-swizzled 16B chunks
#pragma unroll
    for (int p = 0; p < 8; ++p) {
      int cc = p * 256 + tid;            // 0..2047
      int r  = cc >> 7;                  // row 0..15
      int cb = (cc & 127) * 16;          // byte col
      ushort8 v = *(const ushort8*)&whh[(size_t)(out_base + r) * 1024 + cb / 2];
      *(ushort8*)&wsh[((r * 2048 + cb) ^ ((r & 7) << 4)) / 2] = v;
    }
    __syncthreads();

    const char* my_flag_addr = (const char*)flags + (size_t)(w * 16 + (lane & 15)) * 64;
    char* pub_flag_addr = (char*)flags + (size_t)blockIdx.x * 64;

    for (int t = 0; t < 256; ++t) {
      float xi[4];
      if (w == 0) {
#pragma unroll
        for (int jj = 0; jj < 4; ++jj)
          xi[jj] = xin[(size_t)(t * 16 + g * 4 + jj) * 1024 + out_base + n];
      }

      floatx4 s4 = (floatx4){0.f, 0.f, 0.f, 0.f};
      if (t > 0) {
        // acquire: wave w polls its 16 producer flags (one 64B line per lane)
        for (;;) {
          unsigned fv;
          asm volatile("global_load_dword %0, %1, off sc0 sc1" : "=v"(fv) : "v"(my_flag_addr) : "memory");
          asm volatile("s_waitcnt vmcnt(0)" : "+v"(fv) :: "memory");
          if (__all((int)(fv >= (unsigned)t))) break;
        }
        // data: h_{t-1}[batch=n][k = w*256 + ks*32 + g*8 .. +8], ks=0..7
        const char* base = (const char*)hst +
            ((size_t)(t - 1) * 16384 + (size_t)n * 1024 + (size_t)w * 256 + g * 8) * 2;
        uint4v q0, q1, q2, q3, q4, q5, q6, q7;
        for (;;) {
          asm volatile("global_load_dwordx4 %0, %1, off sc0 sc1"            : "=v"(q0) : "v"(base) : "memory");
          asm volatile("global_load_dwordx4 %0, %1, off offset:64 sc0 sc1"  : "=v"(q1) : "v"(base) : "memory");
          asm volatile("global_load_dwordx4 %0, %1, off offset:128 sc0 sc1" : "=v"(q2) : "v"(base) : "memory");
          asm volatile("global_load_dwordx4 %0, %1, off offset:192 sc0 sc1" : "=v"(q3) : "v"(base) : "memory");
          asm volatile("global_load_dwordx4 %0, %1, off offset:256 sc0 sc1" : "=v"(q4) : "v"(base) : "memory");
          asm volatile("global_load_dwordx4 %0, %1, off offset:320 sc0 sc1" : "=v"(q5) : "v"(base) : "memory");
          asm volatile("global_load_dwordx4 %0, %1, off offset:384 sc0 sc1" : "=v"(q6) : "v"(base) : "memory");
          asm volatile("global_load_dwordx4 %0, %1, off offset:448 sc0 sc1" : "=v"(q7) : "v"(base) : "memory");
          asm volatile("s_waitcnt vmcnt(0)"
                       : "+v"(q0), "+v"(q1), "+v"(q2), "+v"(q3),
                         "+v"(q4), "+v"(q5), "+v"(q6), "+v"(q7) :: "memory");
          unsigned bad = 0;
#pragma unroll
          for (int e = 0; e < 4; ++e) {
            bad |= (q0[e] == 0xFFFFFFFFu) | (q1[e] == 0xFFFFFFFFu);
            bad |= (q2[e] == 0xFFFFFFFFu) | (q3[e] == 0xFFFFFFFFu);
            bad |= (q4[e] == 0xFFFFFFFFu) | (q5[e] == 0xFFFFFFFFu);
            bad |= (q6[e] == 0xFFFFFFFFu) | (q7[e] == 0xFFFFFFFFu);
          }
          if (!__any((int)bad)) break;   // backstop; steady state = 1 pass
        }
        floatx4 a0 = (floatx4){0,0,0,0}, a1 = (floatx4){0,0,0,0};
        {
          bf16x8 af0 = __builtin_bit_cast(bf16x8, q0), af1 = __builtin_bit_cast(bf16x8, q1);
          bf16x8 af2 = __builtin_bit_cast(bf16x8, q2), af3 = __builtin_bit_cast(bf16x8, q3);
          bf16x8 af4 = __builtin_bit_cast(bf16x8, q4), af5 = __builtin_bit_cast(bf16x8, q5);
          bf16x8 af6 = __builtin_bit_cast(bf16x8, q6), af7 = __builtin_bit_cast(bf16x8, q7);
#define WB(ks) (*(const bf16x8*)&wsh[((n * 2048 + w * 512 + (ks) * 64 + g * 16) ^ ((n & 7) << 4)) / 2])
          a0 = __builtin_amdgcn_mfma_f32_16x16x32_bf16(af0, WB(0), a0, 0, 0, 0);
          a1 = __builtin_amdgcn_mfma_f32_16x16x32_bf16(af1, WB(1), a1, 0, 0, 0);
          a0 = __builtin_amdgcn_mfma_f32_16x16x32_bf16(af2, WB(2), a0, 0, 0, 0);
          a1 = __builtin_amdgcn_mfma_f32_16x16x32_bf16(af3, WB(3), a1, 0, 0, 0);
          a0 = __builtin_amdgcn_mfma_f32_16x16x32_bf16(af4, WB(4), a0, 0, 0, 0);
          a1 = __builtin_amdgcn_mfma_f32_16x16x32_bf16(af5, WB(5), a1, 0, 0, 0);
          a0 = __builtin_amdgcn_mfma_f32_16x16x32_bf16(af6, WB(6), a0, 0, 0, 0);
          a1 = __builtin_amdgcn_mfma_f32_16x16x32_bf16(af7, WB(7), a1, 0, 0, 0);
#undef WB
        }
        s4 = a0 + a1;
      }

      red[t & 1][w][lane] = s4;
      __syncthreads();                    // partials visible to wave 0

      if (w == 0) {
        floatx4 tot = red[t & 1][0][lane] + red[t & 1][1][lane] +
                      red[t & 1][2][lane] + red[t & 1][3][lane];
        float hv[4];
#pragma unroll
        for (int jj = 0; jj < 4; ++jj) {
          float s = tot[jj] + xi[jj];
          float e = __expf(2.0f * s);         // tanh = 1 - 2/(e^{2s}+1)
          hv[jj] = 1.0f - 2.0f * __builtin_amdgcn_rcpf(e + 1.0f);
        }
        float pv[4];
#pragma unroll
        for (int jj = 0; jj < 4; ++jj) pv[jj] = __shfl_xor(hv[jj], 1);
        const int ev = (lane & 1) == 0;
        const int jA = ev ? 0 : 2, jB = ev ? 1 : 3;
        unsigned dA = ev ? ((unsigned)f2bf(hv[jA]) | ((unsigned)f2bf(pv[jA]) << 16))
                         : ((unsigned)f2bf(pv[jA]) | ((unsigned)f2bf(hv[jA]) << 16));
        unsigned dB = ev ? ((unsigned)f2bf(hv[jB]) | ((unsigned)f2bf(pv[jB]) << 16))
                         : ((unsigned)f2bf(pv[jB]) | ((unsigned)f2bf(hv[jB]) << 16));
        char* rowA = (char*)hst + ((size_t)t * 16384 + (size_t)(g * 4 + jA) * 1024 + out_base + (n & ~1)) * 2;
        char* rowB = (char*)hst + ((size_t)t * 16384 + (size_t)(g * 4 + jB) * 1024 + out_base + (n & ~1)) * 2;
        asm volatile("global_store_dword %0, %1, off sc0 sc1" :: "v"(rowA), "v"(dA) : "memory");
        asm volatile("global_store_dword %0, %1, off sc0 sc1" :: "v"(rowB), "v"(dB) : "memory");
        asm volatile("s_waitcnt vmcnt(0)" ::: "memory");    // data at coherence point
        if (lane == 0) {
          unsigned fval = (unsigned)(t + 1);
          asm volatile("global_store_dword %0, %1, off sc0 sc1" :: "v"(pub_flag_addr), "v"(fval) : "memory");
        }
      }
    }
  } else {
    // ======================= logits GEMM path =======================
    unsigned short* lA = (unsigned short*)smem;            // 16 KB
    unsigned short* lB = (unsigned short*)(smem + 16384);  // 16 KB
    const int gw = blockIdx.x - 64;
    const int wr = w >> 1, wc = w & 1;

    for (int tile = gw; tile < 32 * 250; tile += G) {
      int rb = tile / 250, cb = tile - rb * 250;

      // gate: all 64 flags >= 8*rb+8 (wave 0 polls; throttled)
      if (w == 0) {
        const char* fa = (const char*)flags + (size_t)lane * 64;
        unsigned tgt = (unsigned)(rb * 8 + 8);
        for (;;) {
          unsigned fv;
          asm volatile("global_load_dword %0, %1, off sc0 sc1" : "=v"(fv) : "v"(fa) : "memory");
          asm volatile("s_waitcnt vmcnt(0)" : "+v"(fv) :: "memory");
          if (__all((int)(fv >= tgt))) break;
          __builtin_amdgcn_s_sleep(64);       // ~4k cycles; slack is ~23us/rowblock
        }
      }
      __syncthreads();                        // release all waves

      floatx4 acc[4][4];
#pragma unroll
      for (int m = 0; m < 4; ++m)
#pragma unroll
        for (int nn = 0; nn < 4; ++nn) acc[m][nn] = (floatx4){0.f, 0.f, 0.f, 0.f};

      const size_t rowA0 = (size_t)rb * 128;
      const size_t colB0 = (size_t)cb * 128;

      for (int k0 = 0; k0 < 1024; k0 += 64) {
#pragma unroll
        for (int p = 0; p < 4; ++p) {
          int cc = p * 256 + tid;
          int r  = cc >> 3;
          int c8 = cc & 7;
          const unsigned short* srcA = hst + (rowA0 + r) * 1024 + k0 + c8 * 8;
          const unsigned short* srcB = wyh + (colB0 + r) * 1024 + k0 + c8 * 8;
          __builtin_amdgcn_global_load_lds((const AS1 unsigned int*)srcA,
                                           (AS3 unsigned int*)&lA[cc * 8], 16, 0, 0);
          __builtin_amdgcn_global_load_lds((const AS1 unsigned int*)srcB,
                                           (AS3 unsigned int*)&lB[cc * 8], 16, 0, 0);
        }
        __syncthreads();
#pragma unroll
        for (int kk = 0; kk < 2; ++kk) {
          const int kofs = kk * 32 + (lane >> 4) * 8;
          bf16x8 af[4], bfv[4];
#pragma unroll
          for (int m = 0; m < 4; ++m) {
            int r = wr * 64 + m * 16 + (lane & 15);
            af[m] = *(const bf16x8*)&lA[r * 64 + kofs];
          }
#pragma unroll
          for (int nn = 0; nn < 4; ++nn) {
            int r = wc * 64 + nn * 16 + (lane & 15);
            bfv[nn] = *(const bf16x8*)&lB[r * 64 + kofs];
          }
#pragma unroll
          for (int m = 0; m < 4; ++m)
#pragma unroll
            for (int nn = 0; nn < 4; ++nn)
              acc[m][nn] = __builtin_amdgcn_mfma_f32_16x16x32_bf16(af[m], bfv[nn], acc[m][nn], 0, 0, 0);
        }
        __syncthreads();
      }

      // epilogue: rowmap 2 (r = t*16+b -> b*256+t)
#pragma unroll
      for (int m = 0; m < 4; ++m) {
#pragma unroll
        for (int j = 0; j < 4; ++j) {
          size_t row  = rowA0 + wr * 64 + m * 16 + ((lane >> 4) * 4 + j);
          size_t orow = (row & 15) * 256 + (row >> 4);
          float* crow = out + orow * 32000 + colB0 + wc * 64 + (lane & 15);
#pragma unroll
          for (int nn = 0; nn < 4; ++nn) crow[nn * 16] = acc[m][nn][j];
        }
      }
    }
  }
}

// ---------------- host launch ----------------
extern "C" void kernel_launch(void* const* d_in, const int* in_sizes, int n_in,
                              void* d_out, int out_size, void* d_ws, size_t ws_size,
                              hipStream_t stream) {
  const int*   ids  = (const int*)d_in[0];     // [16,256]
  const float* emb  = (const float*)d_in[1];   // [32000,1024]
  const float* w_hx = (const float*)d_in[2];   // [1024,1024]
  const float* w_hh = (const float*)d_in[3];   // [1024,1024]
  const float* w_yh = (const float*)d_in[4];   // [32000,1024]
  float*       out  = (float*)d_out;           // [16,256,32000]

  const int B = 16, S = 256, H = 1024, V = 32000;
  const int BS = B * S;

  char*  ws  = (char*)d_ws;
  size_t off = 0;
  auto alloc = [&](size_t bytes) {
    size_t cur = off;
    off += (bytes + 255) & ~(size_t)255;
    return (void*)(ws + cur);
  };

  unsigned short* whx_bf = (unsigned short*)alloc((size_t)H * H * 2);
  unsigned short* whh_bf = (unsigned short*)alloc((size_t)H * H * 2);
  unsigned short* wyh_bf = (unsigned short*)alloc((size_t)V * H * 2);
  unsigned short* x_bf   = (unsigned short*)alloc((size_t)BS * H * 2);
  float*          xin    = (float*)alloc((size_t)BS * H * 4);   // [t*16+b][H]
  unsigned short* hst    = (unsigned short*)alloc((size_t)BS * H * 2); // [t][b][H]
  unsigned*       flags  = (unsigned*)alloc(64 * 64);           // 64 flags, 64B stride
  int*            dflag  = (int*)alloc(256);

  // Arm sentinels + flags every call (write-once data-as-flag; replay-safe).
  hipMemsetAsync(hst, 0xFF, (size_t)BS * H * 2, stream);
  hipMemsetAsync(flags, 0, 64 * 64, stream);
  hipMemsetAsync(dflag, 0, 256, stream);

  detect_i64<<<dim3(1), dim3(256), 0, stream>>>(ids, dflag);
  convert_bf16<<<dim3((H * H) / 1024), dim3(256), 0, stream>>>(w_hx, whx_bf, H * H);
  convert_bf16<<<dim3((H * H) / 1024), dim3(256), 0, stream>>>(w_hh, whh_bf, H * H);
  convert_bf16<<<dim3((V * H) / 1024), dim3(256), 0, stream>>>(w_yh, wyh_bf, V * H);
  gather_embed<<<dim3(BS), dim3(256), 0, stream>>>(ids, emb, x_bf, dflag);

  // xin[s*16+b] = x[b*256+s] @ w_hx^T : rowmap=1
  gemm_bt<<<dim3((BS / 128) * (H / 128)), dim3(256), 0, stream>>>(x_bf, whx_bf, xin, BS, H, H, 1);

  // Fused recurrence + logits. Grid must be fully co-resident (spin sync):
  // size from the occupancy API, capped conservatively.
  int occ = 0;
  if (hipOccupancyMaxActiveBlocksPerMultiprocessor(&occ, (const void*)fused_rnn_logits, 256, 0)
          != hipSuccess || occ < 1)
    occ = 1;
  int G = occ * 256 - 64;
  if (G > 448) G = 448;
  if (G < 128) G = 128;
  fused_rnn_logits<<<dim3(64 + G), dim3(256), 0, stream>>>(xin, whh_bf, hst, flags, wyh_bf, out, G);
}